// Round 5
// baseline (366.545 us; speedup 1.0000x reference)
//
#include <hip/hip_runtime.h>
#include <hip/hip_bf16.h>
#include <hip/hip_fp16.h>

typedef __hip_bfloat16 bf16;
typedef unsigned short ushort_t;
typedef __attribute__((ext_vector_type(8))) short bf16x8;
typedef __attribute__((ext_vector_type(16))) float f32x16;

__device__ __forceinline__ float us2f(unsigned short u) {
    unsigned int x = ((unsigned int)u) << 16;
    return __uint_as_float(x);
}
__device__ __forceinline__ ushort_t f2us(float f) {
    return ((__hip_bfloat16_raw)__float2bfloat16(f)).x;
}

// async global->LDS, 16 B per lane. LDS dest = wave-uniform base + lane*16.
__device__ __forceinline__ void gl_lds16(const ushort_t* g, ushort_t* l) {
    __builtin_amdgcn_global_load_lds(
        (const __attribute__((address_space(1))) void*)g,
        (__attribute__((address_space(3))) void*)l, 16, 0, 0);
}

// ---------------------------------------------------------------------------
// Fused input cast (float4): src_b = bf16(src), q_b = bf16(src + pos)
// ---------------------------------------------------------------------------
__global__ __launch_bounds__(256) void cast2_kernel(
    const float* __restrict__ src, const float* __restrict__ pos,
    bf16* __restrict__ src_b, bf16* __restrict__ q_b, int n)
{
    int i = (blockIdx.x * 256 + threadIdx.x) * 4;
    if (i < n) {
        const float4 s4 = *reinterpret_cast<const float4*>(&src[i]);
        const float4 p4 = *reinterpret_cast<const float4*>(&pos[i]);
        int2 sp, qp;
        sp.x = (unsigned)f2us(s4.x) | ((unsigned)f2us(s4.y) << 16);
        sp.y = (unsigned)f2us(s4.z) | ((unsigned)f2us(s4.w) << 16);
        qp.x = (unsigned)f2us(s4.x + p4.x) | ((unsigned)f2us(s4.y + p4.y) << 16);
        qp.y = (unsigned)f2us(s4.z + p4.z) | ((unsigned)f2us(s4.w + p4.w) << 16);
        *reinterpret_cast<int2*>((ushort_t*)src_b + i) = sp;
        *reinterpret_cast<int2*>((ushort_t*)q_b + i) = qp;
    }
}

// ---------------------------------------------------------------------------
// Fused weight prep: all transpose-casts + bias concat in ONE launch.
// ---------------------------------------------------------------------------
__global__ __launch_bounds__(256) void prep_kernel(
    const float* __restrict__ wv, const float* __restrict__ wo,
    const float* __restrict__ wa, const float* __restrict__ wout,
    const float* __restrict__ w1, const float* __restrict__ w2,
    const float* __restrict__ bo, const float* __restrict__ ba,
    bf16* __restrict__ wvt, bf16* __restrict__ wcat, bf16* __restrict__ woutt,
    bf16* __restrict__ w1t, bf16* __restrict__ w2t, float* __restrict__ bcat)
{
    __shared__ float tile[32][33];
    const int b = blockIdx.x;
    const float* W; bf16* Wt; int K, N, tb;
    if (b < 64)        { W = wv;   Wt = wvt;            K = 256;  N = 256;  tb = b; }
    else if (b < 144)  { W = wo;   Wt = wcat;           K = 256;  N = 320;  tb = b - 64; }
    else if (b < 184)  { W = wa;   Wt = wcat + 320*256; K = 256;  N = 160;  tb = b - 144; }
    else if (b < 248)  { W = wout; Wt = woutt;          K = 256;  N = 256;  tb = b - 184; }
    else if (b < 760)  { W = w1;   Wt = w1t;            K = 256;  N = 2048; tb = b - 248; }
    else if (b < 1272) { W = w2;   Wt = w2t;            K = 2048; N = 256;  tb = b - 760; }
    else {
        int i = (b - 1272) * 256 + threadIdx.x;
        if (i < 320) bcat[i] = bo[i];
        else if (i < 480) bcat[i] = ba[i - 320];
        return;
    }
    const int ntn = N >> 5;
    const int nb = (tb % ntn) * 32, kb = (tb / ntn) * 32;
    const int tx = threadIdx.x & 31, ty = threadIdx.x >> 5;  // 32 x 8
    #pragma unroll
    for (int i = 0; i < 32; i += 8) {
        int k = kb + ty + i, n = nb + tx;
        tile[ty + i][tx] = (k < K && n < N) ? W[(size_t)k * N + n] : 0.f;
    }
    __syncthreads();
    #pragma unroll
    for (int i = 0; i < 32; i += 8) {
        int n = nb + ty + i, k = kb + tx;
        if (n < N && k < K)
            Wt[(size_t)n * K + k] = __float2bfloat16(tile[tx][ty + i]);
    }
}

// ---------------------------------------------------------------------------
// MFMA bf16 GEMM (64x128 tile, M-split), swizzled-LDS, DOUBLE-BUFFERED
// K-loop (T3-lite) + vectorized epilogue.
//
// LDS tile layout (both A and B): "super-rows" of 2 K-rows = 128 B, split
// into 8 slots of 16 B. Logical (row, chunk q of 8 bf16) lives at slot
//   phys = (((row&1)<<2) | q) ^ ((row>>1) & 7)
// gl_lds16 dest stays LINEAR; swizzle via pre-permuted GLOBAL source addr.
//
// K-loop: two 12288 B staging buffers. Per K-step: barrier -> issue next
// tile's gl_lds16 into the other buffer -> ds_read+MFMA current buffer.
// The barrier's vmcnt(0) drain thus has a full compute phase of head start
// (prefetch hides global latency); 1 barrier per K-step instead of 2.
// Pair-unrolled (K/32 is always even here) so buffer offsets are
// compile-time immediates (no dynamic indexing -> no scratch, rule #20).
//
// Epilogue unchanged: acc+bias repacked through LDS as float[64][68],
// float4 LDS reads + int2 (4xbf16) full-line global stores.
// ---------------------------------------------------------------------------
template<bool RELU, bool OUT_BF16, bool HAS_RESID, bool RESID_BF16, int NT, int WPE>
__global__ __launch_bounds__(256, WPE) void gemm_mfma_s(
    const ushort_t* __restrict__ A,    // [M][K] bf16
    const ushort_t* __restrict__ Bt,   // [N][K] bf16
    const float* __restrict__ bias,    // [N] f32
    const void* __restrict__ residv,   // [M][N] f32 or bf16
    void* __restrict__ outv, int M, int N, int K, int mtiles)
{
    __shared__ __align__(16) char smemraw[24576];
    ushort_t* Asmem = (ushort_t*)smemraw;          // buf0: A 4 KB @0, B 8 KB @4096
    ushort_t* Bsmem = (ushort_t*)(smemraw + 4096); // buf1 at +12288 B (+6144 us)
    float (*epi)[68] = (float(*)[68])smemraw;      // 64 x 68 f32 = 17408 B overlay

    const int lid = blockIdx.x;
    const int tbk = lid >> 3;
    const int xb = tbk & (NT - 1);
    const int yg = (tbk / NT) * 8 + (lid & 7);
    if (yg >= mtiles) return;
    const int m0 = yg * 64;
    const int n0 = xb * 128;

    const int tid = threadIdx.x;
    const int lane = tid & 63;
    const int wave = tid >> 6;
    const int l32 = lane & 31;
    const int hi  = lane >> 5;
    const int wm = wave >> 1;
    const int wn = wave & 1;

    // ---- staging source pointers (pre-swizzled globals, linear LDS dest) ----
    const int lsup = lane >> 3;   // super-row within the staged 1 KB region
    const int clin = lane & 7;    // linear slot the lane's 16 B land in

    const int gsA = wave * 8 + lsup;          // global super-row in A tile
    const int csA = clin ^ (gsA & 7);         // source slot (involution)
    int rA = m0 + gsA * 2 + (csA >> 2); if (rA > M - 1) rA = M - 1;
    const ushort_t* aP = A + (size_t)rA * K + (csA & 3) * 8;
    ushort_t* aL = Asmem + wave * 512;

    const ushort_t* bP[2]; ushort_t* bL[2];
    #pragma unroll
    for (int i = 0; i < 2; ++i) {
        const int gsB = wave * 16 + i * 8 + lsup;
        const int csB = clin ^ (gsB & 7);
        int rB = n0 + gsB * 2 + (csB >> 2); if (rB > N - 1) rB = N - 1;
        bP[i] = Bt + (size_t)rB * K + (csB & 3) * 8;
        bL[i] = Bsmem + (wave * 16 + i * 8) * 64;
    }

    // ---- fragment read addresses (swizzled, precomputed, loop-invariant) ----
    const int arow = wm * 32 + l32;
    const int asup = arow >> 1;
    const ushort_t* aR[2];
    #pragma unroll
    for (int kw = 0; kw < 2; ++kw) {
        const int q = kw * 2 + hi;
        const int slot = (((arow & 1) << 2) | q) ^ (asup & 7);
        aR[kw] = Asmem + asup * 64 + slot * 8;
    }
    const ushort_t* bR[2][2];
    #pragma unroll
    for (int j = 0; j < 2; ++j) {
        const int brow = wn * 64 + j * 32 + l32;
        const int bsup = brow >> 1;
        #pragma unroll
        for (int kw = 0; kw < 2; ++kw) {
            const int q = kw * 2 + hi;
            const int slot = (((brow & 1) << 2) | q) ^ (bsup & 7);
            bR[j][kw] = Bsmem + bsup * 64 + slot * 8;
        }
    }

    f32x16 acc[2] = {};

    auto stage = [&](int ofs) {  // ofs in ushorts: 0 = buf0, 6144 = buf1
        gl_lds16(aP, aL + ofs);             aP    += 32;
        gl_lds16(bP[0], bL[0] + ofs);       bP[0] += 32;
        gl_lds16(bP[1], bL[1] + ofs);       bP[1] += 32;
    };
    auto compute = [&](int ofs) {
        #pragma unroll
        for (int kw = 0; kw < 2; ++kw) {
            const bf16x8 af = *reinterpret_cast<const bf16x8*>(aR[kw] + ofs);
            #pragma unroll
            for (int j = 0; j < 2; ++j)
                acc[j] = __builtin_amdgcn_mfma_f32_32x32x16_bf16(
                    af, *reinterpret_cast<const bf16x8*>(bR[j][kw] + ofs),
                    acc[j], 0, 0, 0);
        }
    };

    const int ntile = K >> 5;          // always even (K = 256 or 2048)
    stage(0);                          // prologue: tile 0 -> buf0
    for (int t = 0; t < ntile; t += 2) {
        __syncthreads();               // buf0 (tile t) ready; buf1 readers done
        stage(6144);                   // tile t+1 -> buf1 (flies over compute)
        compute(0);
        __syncthreads();               // buf1 (tile t+1) ready; buf0 readers done
        if (t + 2 < ntile) stage(0);   // tile t+2 -> buf0
        compute(6144);
    }
    __syncthreads();                   // all ds_reads done before epi overlay

    // ---- epilogue: LDS repack (f32) + vectorized full-line stores ----
    #pragma unroll
    for (int half = 0; half < 2; ++half) {
        if (wn == half) {
            #pragma unroll
            for (int j = 0; j < 2; ++j) {
                const int coll = j * 32 + l32;          // 0..63 within half
                const int n = n0 + half * 64 + coll;
                const float bv = (n < N) ? bias[n] : 0.f;
                #pragma unroll
                for (int r = 0; r < 16; ++r) {
                    const int row = wm * 32 + hi * 4 + (r & 3) + (r >> 2) * 8;
                    epi[row][coll] = acc[j][r] + bv;
                }
            }
        }
        __syncthreads();
        #pragma unroll
        for (int i = 0; i < 4; ++i) {
            const int idx = i * 256 + tid;
            const int row = idx >> 4;
            const int c4  = idx & 15;
            const int m = m0 + row;
            const int n = n0 + half * 64 + c4 * 4;
            if (m < M && n + 3 < N) {
                float4 v = *reinterpret_cast<const float4*>(&epi[row][c4 * 4]);
                if (HAS_RESID) {
                    if (RESID_BF16) {
                        const int2 rw = *reinterpret_cast<const int2*>(
                            (const ushort_t*)residv + (size_t)m * N + n);
                        v.x += us2f((ushort_t)((unsigned)rw.x & 0xffffu));
                        v.y += us2f((ushort_t)((unsigned)rw.x >> 16));
                        v.z += us2f((ushort_t)((unsigned)rw.y & 0xffffu));
                        v.w += us2f((ushort_t)((unsigned)rw.y >> 16));
                    } else {
                        const float4 r4 = *reinterpret_cast<const float4*>(
                            (const float*)residv + (size_t)m * N + n);
                        v.x += r4.x; v.y += r4.y; v.z += r4.z; v.w += r4.w;
                    }
                }
                if (RELU) {
                    v.x = fmaxf(v.x, 0.f); v.y = fmaxf(v.y, 0.f);
                    v.z = fmaxf(v.z, 0.f); v.w = fmaxf(v.w, 0.f);
                }
                if (OUT_BF16) {
                    int2 pk;
                    pk.x = (unsigned)f2us(v.x) | ((unsigned)f2us(v.y) << 16);
                    pk.y = (unsigned)f2us(v.z) | ((unsigned)f2us(v.w) << 16);
                    *reinterpret_cast<int2*>((ushort_t*)outv + (size_t)m * N + n) = pk;
                } else {
                    *reinterpret_cast<float4*>((float*)outv + (size_t)m * N + n) = v;
                }
            }
        }
        if (half == 0) __syncthreads();
    }
}

// ---------------------------------------------------------------------------
// MS-deformable attention v6 (unchanged from R4 — at ~L3-BW structural limit).
// ---------------------------------------------------------------------------
__global__ __launch_bounds__(256) void msda_kernel_v6(
    const ushort_t* __restrict__ og,     // [M,480] bf16: offs 0..319, logits 320..479
    const float* __restrict__ refp,      // [M,10]
    const ushort_t* __restrict__ value,  // [M,256] bf16 = (B,L,H,32)
    bf16* __restrict__ out,              // [M,256] bf16
    int M, int L)
{
    const int tid = threadIdx.x;
    const int qbase = blockIdx.x * 8;

    __shared__ float s_attn[8][160];   // 5120 B
    __shared__ int2  s_off[1280];      // 10240 B
    __shared__ int2  s_wh[1280];       // 10240 B -> total 25600 B

    for (int i = tid; i < 1280; i += 256) {
        int q = i / 160, j = i - q * 160;
        int qq = qbase + q;
        s_attn[q][j] = (qq < M) ? us2f(og[(size_t)qq * 480 + 320 + j]) : 0.f;
    }
    __syncthreads();

    if (tid < 64) {
        float* a = &s_attn[tid >> 3][(tid & 7) * 20];
        float mx = -1e30f;
        #pragma unroll
        for (int i = 0; i < 20; ++i) mx = fmaxf(mx, a[i]);
        float ssum = 0.f;
        #pragma unroll
        for (int i = 0; i < 20; ++i) {
            float e = __expf(a[i] - mx);
            a[i] = e;
            ssum += e;
        }
        float inv = 1.f / ssum;
        #pragma unroll
        for (int i = 0; i < 20; ++i) a[i] *= inv;
    }
    __syncthreads();

    #pragma unroll
    for (int it = 0; it < 5; ++it) {
        const int t = tid + it * 256;
        const int q  = t / 160;
        const int r  = t - q * 160;
        const int l  = (r - (r / 20) * 20) >> 2;
        const int qq = qbase + q;

        int2 offp = {0, 0};
        __half2 h01 = __floats2half2_rn(0.f, 0.f);
        __half2 h23 = h01;
        if (qq < M) {
            const int Wi = (l == 0) ? 100 : (l == 1) ? 50 : (l == 2) ? 25
                         : (l == 3) ? 13 : 7;
            const int s0 = (l == 0) ? 0 : (l == 1) ? 10000 : (l == 2) ? 12500
                         : (l == 3) ? 13125 : 13294;
            const float Wf = (float)Wi;
            const float ox = us2f(og[(size_t)qq * 480 + r * 2]);
            const float oy = us2f(og[(size_t)qq * 480 + r * 2 + 1]);
            const float2 rf = *reinterpret_cast<const float2*>(
                &refp[(size_t)qq * 10 + l * 2]);
            const float a = s_attn[q][r];

            const float px = fmaf(rf.x, Wf, -0.5f) + ox;
            const float py = fmaf(rf.y, Wf, -0.5f) + oy;
            const float x0f = floorf(px);
            const float y0f = floorf(py);
            const float lx = px - x0f;
            const float ly = py - y0f;
            const int x0 = (int)x0f;
            const int y0 = (int)y0f;

            const float wx0v = (x0 >= 0 && x0 < Wi) ? (1.f - lx) : 0.f;
            const float wx1v = (x0 + 1 >= 0 && x0 + 1 < Wi) ? lx : 0.f;
            const float wy0v = (y0 >= 0 && y0 < Wi) ? (1.f - ly) : 0.f;
            const float wy1v = (y0 + 1 >= 0 && y0 + 1 < Wi) ? ly : 0.f;

            const int c0 = min(max(x0, 0), Wi - 2);
            const int r0 = min(max(y0, 0), Wi - 2);
            const float swx0 = (x0 == c0 ? wx0v : 0.f) + (x0 + 1 == c0 ? wx1v : 0.f);
            const float swx1 = (x0 == c0 + 1 ? wx0v : 0.f) + (x0 + 1 == c0 + 1 ? wx1v : 0.f);
            const float swy0 = (y0 == r0 ? wy0v : 0.f) + (y0 + 1 == r0 ? wy1v : 0.f);
            const float swy1 = (y0 == r0 + 1 ? wy0v : 0.f) + (y0 + 1 == r0 + 1 ? wy1v : 0.f);

            offp.x = (s0 + r0 * Wi + c0) * 512;
            offp.y = offp.x + Wi * 512;
            h01 = __floats2half2_rn(a * swx0 * swy0, a * swx1 * swy0);
            h23 = __floats2half2_rn(a * swx0 * swy1, a * swx1 * swy1);
        }
        s_off[t] = offp;
        union { __half2 h; int i; } c0u, c1u;
        c0u.h = h01; c1u.h = h23;
        int2 wpk; wpk.x = c0u.i; wpk.y = c1u.i;
        s_wh[t] = wpk;
    }
    __syncthreads();

    const int qi  = tid >> 5;
    const int g   = tid & 31;
    const int h   = g >> 2;
    const int sub = g & 3;
    const int bq = qbase + qi;
    if (bq >= M) return;
    const int b = bq / L;

    const char* vb = (const char*)value + (size_t)b * L * 512 + h * 64 + sub * 16;

    float acc[8] = {};
    const int tb = qi * 160 + h * 20;
    #pragma unroll 2
    for (int p = 0; p < 20; ++p) {
        const int2 off = s_off[tb + p];
        const int2 whp = s_wh[tb + p];
        const int4 u00 = *reinterpret_cast<const int4*>(vb + off.x);
        const int4 u10 = *reinterpret_cast<const int4*>(vb + off.x + 512);
        const int4 u01 = *reinterpret_cast<const int4*>(vb + off.y);
        const int4 u11 = *reinterpret_cast<const int4*>(vb + off.y + 512);
        union { int i; __half2 h; } w0u, w1u;
        w0u.i = whp.x; w1u.i = whp.y;
        const float2 w01 = __half22float2(w0u.h);
        const float2 w23 = __half22float2(w1u.h);
        #define ACC4(u, wt)                                                        \
            acc[0] = fmaf(wt, __uint_as_float((unsigned)(u).x << 16), acc[0]);      \
            acc[1] = fmaf(wt, __uint_as_float((unsigned)(u).x & 0xffff0000u), acc[1]); \
            acc[2] = fmaf(wt, __uint_as_float((unsigned)(u).y << 16), acc[2]);      \
            acc[3] = fmaf(wt, __uint_as_float((unsigned)(u).y & 0xffff0000u), acc[3]); \
            acc[4] = fmaf(wt, __uint_as_float((unsigned)(u).z << 16), acc[4]);      \
            acc[5] = fmaf(wt, __uint_as_float((unsigned)(u).z & 0xffff0000u), acc[5]); \
            acc[6] = fmaf(wt, __uint_as_float((unsigned)(u).w << 16), acc[6]);      \
            acc[7] = fmaf(wt, __uint_as_float((unsigned)(u).w & 0xffff0000u), acc[7]);
        ACC4(u00, w01.x)
        ACC4(u10, w01.y)
        ACC4(u01, w23.x)
        ACC4(u11, w23.y)
        #undef ACC4
    }

    ushort_t o[8];
    #pragma unroll
    for (int i = 0; i < 8; ++i) o[i] = f2us(acc[i]);
    int4 pkt;
    pkt.x = (int)o[0] | ((int)o[1] << 16);
    pkt.y = (int)o[2] | ((int)o[3] << 16);
    pkt.z = (int)o[4] | ((int)o[5] << 16);
    pkt.w = (int)o[6] | ((int)o[7] << 16);
    *reinterpret_cast<int4*>((ushort_t*)out + (size_t)bq * 256 + h * 32 + sub * 8) = pkt;
}

// ---------------------------------------------------------------------------
// LayerNorm over 256, bf16 input. Block = 4 waves = 4 rows, wave-per-row,
// shuffle-only. OUT_BF16: bf16 out (LN1->x_b) else f32 out (LN2->d_out).
// ---------------------------------------------------------------------------
template<bool OUT_BF16>
__global__ __launch_bounds__(256) void ln_kernel(
    const ushort_t* __restrict__ yb, const float* __restrict__ g,
    const float* __restrict__ bta, void* __restrict__ outv, int M)
{
    const int wave = threadIdx.x >> 6, lane = threadIdx.x & 63;
    const int row = blockIdx.x * 4 + wave;
    if (row >= M) return;
    const int2 raw = *reinterpret_cast<const int2*>(&yb[(size_t)row * 256 + lane * 4]);
    float v0 = us2f((ushort_t)((unsigned)raw.x & 0xffffu));
    float v1 = us2f((ushort_t)((unsigned)raw.x >> 16));
    float v2 = us2f((ushort_t)((unsigned)raw.y & 0xffffu));
    float v3 = us2f((ushort_t)((unsigned)raw.y >> 16));
    float s  = v0 + v1 + v2 + v3;
    float ss = v0 * v0 + v1 * v1 + v2 * v2 + v3 * v3;
    #pragma unroll
    for (int o = 32; o > 0; o >>= 1) {
        s += __shfl_down(s, o);
        ss += __shfl_down(ss, o);
    }
    s = __shfl(s, 0);
    ss = __shfl(ss, 0);
    const float mean = s * (1.f / 256.f);
    const float var = ss * (1.f / 256.f) - mean * mean;
    const float rs = rsqrtf(var + 1e-5f);
    const float4 g4 = *reinterpret_cast<const float4*>(&g[lane * 4]);
    const float4 b4 = *reinterpret_cast<const float4*>(&bta[lane * 4]);
    float4 o4;
    o4.x = (v0 - mean) * rs * g4.x + b4.x;
    o4.y = (v1 - mean) * rs * g4.y + b4.y;
    o4.z = (v2 - mean) * rs * g4.z + b4.z;
    o4.w = (v3 - mean) * rs * g4.w + b4.w;
    if (OUT_BF16) {
        int2 pk;
        pk.x = (unsigned)f2us(o4.x) | ((unsigned)f2us(o4.y) << 16);
        pk.y = (unsigned)f2us(o4.z) | ((unsigned)f2us(o4.w) << 16);
        *reinterpret_cast<int2*>((ushort_t*)outv + (size_t)row * 256 + lane * 4) = pk;
    } else {
        *reinterpret_cast<float4*>((float*)outv + (size_t)row * 256 + lane * 4) = o4;
    }
}

// ---------------------------------------------------------------------------
extern "C" void kernel_launch(void* const* d_in, const int* in_sizes, int n_in,
                              void* d_out, int out_size, void* d_ws, size_t ws_size,
                              hipStream_t stream)
{
    const int B = 2, L = 13343, C = 256, FF = 2048;
    const int M = B * L;  // 26686

    const float* src  = (const float*)d_in[0];
    const float* pos  = (const float*)d_in[1];
    const float* refp = (const float*)d_in[2];
    const float* wv   = (const float*)d_in[3];
    const float* bv   = (const float*)d_in[4];
    const float* wo   = (const float*)d_in[5];
    const float* bo   = (const float*)d_in[6];
    const float* wa   = (const float*)d_in[7];
    const float* ba   = (const float*)d_in[8];
    const float* wout = (const float*)d_in[9];
    const float* bout = (const float*)d_in[10];
    const float* ln1g = (const float*)d_in[11];
    const float* ln1b = (const float*)d_in[12];
    const float* w1   = (const float*)d_in[13];
    const float* b1   = (const float*)d_in[14];
    const float* w2   = (const float*)d_in[15];
    const float* b2   = (const float*)d_in[16];
    const float* ln2g = (const float*)d_in[17];
    const float* ln2b = (const float*)d_in[18];

    char* ws = (char*)d_ws;
    const size_t MB = 1ull << 20;
    // ---- workspace overlay (peak ~155 MB) ----
    bf16*  src_b  = (bf16*)(ws + 0);         // 13.7 MB
    bf16*  q_b    = (bf16*)(ws + 14 * MB);   // 13.7
    bf16*  val_b  = (bf16*)(ws + 28 * MB);   // 13.7
    bf16*  og     = (bf16*)(ws + 42 * MB);   // M*480 bf16 = 25.6 -> ends 67.6
    bf16*  acc_b  = (bf16*)(ws + 95 * MB);   // 13.7 -> ends 108.7
    bf16*  h_b    = (bf16*)(ws + 0);         // M*2048 bf16 = 109.3 (overlays dead)
    bf16*  y      = (bf16*)(ws + 110 * MB);  // 13.7 bf16 (dead after LN1)
    bf16*  z      = (bf16*)(ws + 110 * MB);  // overlays y (bf16)
    bf16*  x_b    = (bf16*)(ws + 138 * MB);  // 13.7 (resid + FFN1 input)
    bf16* wvt    = (bf16*)(ws + 152 * MB);   // 256*256
    bf16* wcat   = wvt + 256 * 256;          // 480*256
    bf16* woutt  = wcat + 480 * 256;         // 256*256
    bf16* w1t    = woutt + 256 * 256;        // 2048*256
    bf16* w2t    = w1t + 2048 * 256;         // 256*2048
    float* bcat  = (float*)(w2t + 256 * 2048); // 480 f32, ends ~154.6 MB
    (void)ws_size; (void)n_in; (void)in_sizes; (void)out_size;

    const int mt64 = (M + 63) / 64;        // 417
    const int gm8  = (mt64 + 7) / 8;       // 53
    const int lnb  = (M + 3) / 4;          // 6672

    // ---- fused weight prep (one launch) ----
    prep_kernel<<<1274, 256, 0, stream>>>(wv, wo, wa, wout, w1, w2, bo, ba,
                                          wvt, wcat, woutt, w1t, w2t, bcat);

    // ---- fused activation casts (float4) ----
    cast2_kernel<<<(M * C / 4 + 255) / 256, 256, 0, stream>>>(
        src, pos, src_b, q_b, M * C);

    // value = src @ wv + bv  (bf16)  [NT=2]
    gemm_mfma_s<false, true, false, false, 2, 4><<<gm8 * 16, 256, 0, stream>>>(
        (const ushort_t*)src_b, (const ushort_t*)wvt, bv, nullptr, val_b,
        M, 256, 256, mt64);

    // og = q @ [wo|wa] + [bo|ba]  (bf16, N=480)  [NT=4]
    gemm_mfma_s<false, true, false, false, 4, 4><<<gm8 * 32, 256, 0, stream>>>(
        (const ushort_t*)q_b, (const ushort_t*)wcat, bcat, nullptr, og,
        M, 480, 256, mt64);

    // deformable attention -> acc_b (bf16)
    msda_kernel_v6<<<(M + 7) / 8, 256, 0, stream>>>(
        (const ushort_t*)og, refp, (const ushort_t*)val_b, acc_b, M, L);

    // y = acc @ wout + bout + src  (bf16 out, f32 resid)  [NT=2]
    gemm_mfma_s<false, true, true, false, 2, 4><<<gm8 * 16, 256, 0, stream>>>(
        (const ushort_t*)acc_b, (const ushort_t*)woutt, bout, src, y,
        M, 256, 256, mt64);

    // x_b = LN1(y)  (bf16 in, bf16 out)
    ln_kernel<true><<<lnb, 256, 0, stream>>>(
        (const ushort_t*)y, ln1g, ln1b, x_b, M);

    // h = relu(x @ w1 + b1)  (bf16, N=2048)  [NT=16]
    gemm_mfma_s<true, true, false, false, 16, 4><<<gm8 * 128, 256, 0, stream>>>(
        (const ushort_t*)x_b, (const ushort_t*)w1t, b1, nullptr, h_b,
        M, FF, 256, mt64);

    // z = h @ w2 + b2 + x  (bf16 out, bf16 resid = x_b)  [NT=2]
    gemm_mfma_s<false, true, true, true, 2, 4><<<gm8 * 16, 256, 0, stream>>>(
        (const ushort_t*)h_b, (const ushort_t*)w2t, b2, x_b, z,
        M, 256, FF, mt64);

    // out = LN2(z)  (bf16 in, f32 out)
    ln_kernel<false><<<lnb, 256, 0, stream>>>(
        (const ushort_t*)z, ln2g, ln2b, (float*)d_out, M);
}

// Round 6
// 353.953 us; speedup vs baseline: 1.0356x; 1.0356x over previous
//
#include <hip/hip_runtime.h>
#include <hip/hip_bf16.h>
#include <hip/hip_fp16.h>

typedef __hip_bfloat16 bf16;
typedef unsigned short ushort_t;
typedef __attribute__((ext_vector_type(8))) short bf16x8;
typedef __attribute__((ext_vector_type(16))) float f32x16;

__device__ __forceinline__ float us2f(unsigned short u) {
    unsigned int x = ((unsigned int)u) << 16;
    return __uint_as_float(x);
}
__device__ __forceinline__ ushort_t f2us(float f) {
    return ((__hip_bfloat16_raw)__float2bfloat16(f)).x;
}

// async global->LDS, 16 B per lane. LDS dest = wave-uniform base + lane*16.
__device__ __forceinline__ void gl_lds16(const ushort_t* g, ushort_t* l) {
    __builtin_amdgcn_global_load_lds(
        (const __attribute__((address_space(1))) void*)g,
        (__attribute__((address_space(3))) void*)l, 16, 0, 0);
}

// ---------------------------------------------------------------------------
// Fused input cast (float4): src_b = bf16(src), q_b = bf16(src + pos)
// ---------------------------------------------------------------------------
__global__ __launch_bounds__(256) void cast2_kernel(
    const float* __restrict__ src, const float* __restrict__ pos,
    bf16* __restrict__ src_b, bf16* __restrict__ q_b, int n)
{
    int i = (blockIdx.x * 256 + threadIdx.x) * 4;
    if (i < n) {
        const float4 s4 = *reinterpret_cast<const float4*>(&src[i]);
        const float4 p4 = *reinterpret_cast<const float4*>(&pos[i]);
        int2 sp, qp;
        sp.x = (unsigned)f2us(s4.x) | ((unsigned)f2us(s4.y) << 16);
        sp.y = (unsigned)f2us(s4.z) | ((unsigned)f2us(s4.w) << 16);
        qp.x = (unsigned)f2us(s4.x + p4.x) | ((unsigned)f2us(s4.y + p4.y) << 16);
        qp.y = (unsigned)f2us(s4.z + p4.z) | ((unsigned)f2us(s4.w + p4.w) << 16);
        *reinterpret_cast<int2*>((ushort_t*)src_b + i) = sp;
        *reinterpret_cast<int2*>((ushort_t*)q_b + i) = qp;
    }
}

// ---------------------------------------------------------------------------
// Fused weight prep: all transpose-casts + bias concat in ONE launch.
// ---------------------------------------------------------------------------
__global__ __launch_bounds__(256) void prep_kernel(
    const float* __restrict__ wv, const float* __restrict__ wo,
    const float* __restrict__ wa, const float* __restrict__ wout,
    const float* __restrict__ w1, const float* __restrict__ w2,
    const float* __restrict__ bo, const float* __restrict__ ba,
    bf16* __restrict__ wvt, bf16* __restrict__ wcat, bf16* __restrict__ woutt,
    bf16* __restrict__ w1t, bf16* __restrict__ w2t, float* __restrict__ bcat)
{
    __shared__ float tile[32][33];
    const int b = blockIdx.x;
    const float* W; bf16* Wt; int K, N, tb;
    if (b < 64)        { W = wv;   Wt = wvt;            K = 256;  N = 256;  tb = b; }
    else if (b < 144)  { W = wo;   Wt = wcat;           K = 256;  N = 320;  tb = b - 64; }
    else if (b < 184)  { W = wa;   Wt = wcat + 320*256; K = 256;  N = 160;  tb = b - 144; }
    else if (b < 248)  { W = wout; Wt = woutt;          K = 256;  N = 256;  tb = b - 184; }
    else if (b < 760)  { W = w1;   Wt = w1t;            K = 256;  N = 2048; tb = b - 248; }
    else if (b < 1272) { W = w2;   Wt = w2t;            K = 2048; N = 256;  tb = b - 760; }
    else {
        int i = (b - 1272) * 256 + threadIdx.x;
        if (i < 320) bcat[i] = bo[i];
        else if (i < 480) bcat[i] = ba[i - 320];
        return;
    }
    const int ntn = N >> 5;
    const int nb = (tb % ntn) * 32, kb = (tb / ntn) * 32;
    const int tx = threadIdx.x & 31, ty = threadIdx.x >> 5;  // 32 x 8
    #pragma unroll
    for (int i = 0; i < 32; i += 8) {
        int k = kb + ty + i, n = nb + tx;
        tile[ty + i][tx] = (k < K && n < N) ? W[(size_t)k * N + n] : 0.f;
    }
    __syncthreads();
    #pragma unroll
    for (int i = 0; i < 32; i += 8) {
        int n = nb + ty + i, k = kb + tx;
        if (n < N && k < K)
            Wt[(size_t)n * K + k] = __float2bfloat16(tile[tx][ty + i]);
    }
}

// ---------------------------------------------------------------------------
// MFMA bf16 GEMM (64x128 tile, M-split), swizzled-LDS, DOUBLE-BUFFERED
// K-loop (T3-lite) + vectorized epilogue.  (unchanged from R5)
// ---------------------------------------------------------------------------
template<bool RELU, bool OUT_BF16, bool HAS_RESID, bool RESID_BF16, int NT, int WPE>
__global__ __launch_bounds__(256, WPE) void gemm_mfma_s(
    const ushort_t* __restrict__ A,    // [M][K] bf16
    const ushort_t* __restrict__ Bt,   // [N][K] bf16
    const float* __restrict__ bias,    // [N] f32
    const void* __restrict__ residv,   // [M][N] f32 or bf16
    void* __restrict__ outv, int M, int N, int K, int mtiles)
{
    __shared__ __align__(16) char smemraw[24576];
    ushort_t* Asmem = (ushort_t*)smemraw;          // buf0: A 4 KB @0, B 8 KB @4096
    ushort_t* Bsmem = (ushort_t*)(smemraw + 4096); // buf1 at +12288 B (+6144 us)
    float (*epi)[68] = (float(*)[68])smemraw;      // 64 x 68 f32 = 17408 B overlay

    const int lid = blockIdx.x;
    const int tbk = lid >> 3;
    const int xb = tbk & (NT - 1);
    const int yg = (tbk / NT) * 8 + (lid & 7);
    if (yg >= mtiles) return;
    const int m0 = yg * 64;
    const int n0 = xb * 128;

    const int tid = threadIdx.x;
    const int lane = tid & 63;
    const int wave = tid >> 6;
    const int l32 = lane & 31;
    const int hi  = lane >> 5;
    const int wm = wave >> 1;
    const int wn = wave & 1;

    // ---- staging source pointers (pre-swizzled globals, linear LDS dest) ----
    const int lsup = lane >> 3;   // super-row within the staged 1 KB region
    const int clin = lane & 7;    // linear slot the lane's 16 B land in

    const int gsA = wave * 8 + lsup;          // global super-row in A tile
    const int csA = clin ^ (gsA & 7);         // source slot (involution)
    int rA = m0 + gsA * 2 + (csA >> 2); if (rA > M - 1) rA = M - 1;
    const ushort_t* aP = A + (size_t)rA * K + (csA & 3) * 8;
    ushort_t* aL = Asmem + wave * 512;

    const ushort_t* bP[2]; ushort_t* bL[2];
    #pragma unroll
    for (int i = 0; i < 2; ++i) {
        const int gsB = wave * 16 + i * 8 + lsup;
        const int csB = clin ^ (gsB & 7);
        int rB = n0 + gsB * 2 + (csB >> 2); if (rB > N - 1) rB = N - 1;
        bP[i] = Bt + (size_t)rB * K + (csB & 3) * 8;
        bL[i] = Bsmem + (wave * 16 + i * 8) * 64;
    }

    // ---- fragment read addresses (swizzled, precomputed, loop-invariant) ----
    const int arow = wm * 32 + l32;
    const int asup = arow >> 1;
    const ushort_t* aR[2];
    #pragma unroll
    for (int kw = 0; kw < 2; ++kw) {
        const int q = kw * 2 + hi;
        const int slot = (((arow & 1) << 2) | q) ^ (asup & 7);
        aR[kw] = Asmem + asup * 64 + slot * 8;
    }
    const ushort_t* bR[2][2];
    #pragma unroll
    for (int j = 0; j < 2; ++j) {
        const int brow = wn * 64 + j * 32 + l32;
        const int bsup = brow >> 1;
        #pragma unroll
        for (int kw = 0; kw < 2; ++kw) {
            const int q = kw * 2 + hi;
            const int slot = (((brow & 1) << 2) | q) ^ (bsup & 7);
            bR[j][kw] = Bsmem + bsup * 64 + slot * 8;
        }
    }

    f32x16 acc[2] = {};

    auto stage = [&](int ofs) {  // ofs in ushorts: 0 = buf0, 6144 = buf1
        gl_lds16(aP, aL + ofs);             aP    += 32;
        gl_lds16(bP[0], bL[0] + ofs);       bP[0] += 32;
        gl_lds16(bP[1], bL[1] + ofs);       bP[1] += 32;
    };
    auto compute = [&](int ofs) {
        #pragma unroll
        for (int kw = 0; kw < 2; ++kw) {
            const bf16x8 af = *reinterpret_cast<const bf16x8*>(aR[kw] + ofs);
            #pragma unroll
            for (int j = 0; j < 2; ++j)
                acc[j] = __builtin_amdgcn_mfma_f32_32x32x16_bf16(
                    af, *reinterpret_cast<const bf16x8*>(bR[j][kw] + ofs),
                    acc[j], 0, 0, 0);
        }
    };

    const int ntile = K >> 5;          // always even (K = 256 or 2048)
    stage(0);                          // prologue: tile 0 -> buf0
    for (int t = 0; t < ntile; t += 2) {
        __syncthreads();               // buf0 (tile t) ready; buf1 readers done
        stage(6144);                   // tile t+1 -> buf1 (flies over compute)
        compute(0);
        __syncthreads();               // buf1 (tile t+1) ready; buf0 readers done
        if (t + 2 < ntile) stage(0);   // tile t+2 -> buf0
        compute(6144);
    }
    __syncthreads();                   // all ds_reads done before epi overlay

    // ---- epilogue: LDS repack (f32) + vectorized full-line stores ----
    #pragma unroll
    for (int half = 0; half < 2; ++half) {
        if (wn == half) {
            #pragma unroll
            for (int j = 0; j < 2; ++j) {
                const int coll = j * 32 + l32;          // 0..63 within half
                const int n = n0 + half * 64 + coll;
                const float bv = (n < N) ? bias[n] : 0.f;
                #pragma unroll
                for (int r = 0; r < 16; ++r) {
                    const int row = wm * 32 + hi * 4 + (r & 3) + (r >> 2) * 8;
                    epi[row][coll] = acc[j][r] + bv;
                }
            }
        }
        __syncthreads();
        #pragma unroll
        for (int i = 0; i < 4; ++i) {
            const int idx = i * 256 + tid;
            const int row = idx >> 4;
            const int c4  = idx & 15;
            const int m = m0 + row;
            const int n = n0 + half * 64 + c4 * 4;
            if (m < M && n + 3 < N) {
                float4 v = *reinterpret_cast<const float4*>(&epi[row][c4 * 4]);
                if (HAS_RESID) {
                    if (RESID_BF16) {
                        const int2 rw = *reinterpret_cast<const int2*>(
                            (const ushort_t*)residv + (size_t)m * N + n);
                        v.x += us2f((ushort_t)((unsigned)rw.x & 0xffffu));
                        v.y += us2f((ushort_t)((unsigned)rw.x >> 16));
                        v.z += us2f((ushort_t)((unsigned)rw.y & 0xffffu));
                        v.w += us2f((ushort_t)((unsigned)rw.y >> 16));
                    } else {
                        const float4 r4 = *reinterpret_cast<const float4*>(
                            (const float*)residv + (size_t)m * N + n);
                        v.x += r4.x; v.y += r4.y; v.z += r4.z; v.w += r4.w;
                    }
                }
                if (RELU) {
                    v.x = fmaxf(v.x, 0.f); v.y = fmaxf(v.y, 0.f);
                    v.z = fmaxf(v.z, 0.f); v.w = fmaxf(v.w, 0.f);
                }
                if (OUT_BF16) {
                    int2 pk;
                    pk.x = (unsigned)f2us(v.x) | ((unsigned)f2us(v.y) << 16);
                    pk.y = (unsigned)f2us(v.z) | ((unsigned)f2us(v.w) << 16);
                    *reinterpret_cast<int2*>((ushort_t*)outv + (size_t)m * N + n) = pk;
                } else {
                    *reinterpret_cast<float4*>((float*)outv + (size_t)m * N + n) = v;
                }
            }
        }
        if (half == 0) __syncthreads();
    }
}

// ---------------------------------------------------------------------------
// MS-deformable attention v7 = v6 + batch->XCD block remap.
// Grid is 3336 = 8*417; batch 0 = works [0,1668) = 4*417 exactly.
// XCD assignment is blockIdx%8 round-robin, so work = (bid&7)*per + (bid>>3)
// gives XCD x the contiguous work range [x*per, (x+1)*per): XCDs 0-3 only
// touch batch 0's value half (6.8 MB), XCDs 4-7 only batch 1's -> per-XCD
// L2 random working set halves (13.7 -> 6.8 MB vs 4 MB L2). Bijective.
// ---------------------------------------------------------------------------
__global__ __launch_bounds__(256) void msda_kernel_v7(
    const ushort_t* __restrict__ og,     // [M,480] bf16: offs 0..319, logits 320..479
    const float* __restrict__ refp,      // [M,10]
    const ushort_t* __restrict__ value,  // [M,256] bf16 = (B,L,H,32)
    bf16* __restrict__ out,              // [M,256] bf16
    int M, int L)
{
    const int tid = threadIdx.x;
    const int nb = gridDim.x;
    int wk = blockIdx.x;
    if ((nb & 7) == 0) {                       // bijective XCD remap
        const int per = nb >> 3;
        wk = (blockIdx.x & 7) * per + (blockIdx.x >> 3);
    }
    const int qbase = wk * 8;

    __shared__ float s_attn[8][160];   // 5120 B
    __shared__ int2  s_off[1280];      // 10240 B
    __shared__ int2  s_wh[1280];       // 10240 B -> total 25600 B

    for (int i = tid; i < 1280; i += 256) {
        int q = i / 160, j = i - q * 160;
        int qq = qbase + q;
        s_attn[q][j] = (qq < M) ? us2f(og[(size_t)qq * 480 + 320 + j]) : 0.f;
    }
    __syncthreads();

    if (tid < 64) {
        float* a = &s_attn[tid >> 3][(tid & 7) * 20];
        float mx = -1e30f;
        #pragma unroll
        for (int i = 0; i < 20; ++i) mx = fmaxf(mx, a[i]);
        float ssum = 0.f;
        #pragma unroll
        for (int i = 0; i < 20; ++i) {
            float e = __expf(a[i] - mx);
            a[i] = e;
            ssum += e;
        }
        float inv = 1.f / ssum;
        #pragma unroll
        for (int i = 0; i < 20; ++i) a[i] *= inv;
    }
    __syncthreads();

    #pragma unroll
    for (int it = 0; it < 5; ++it) {
        const int t = tid + it * 256;
        const int q  = t / 160;
        const int r  = t - q * 160;
        const int l  = (r - (r / 20) * 20) >> 2;
        const int qq = qbase + q;

        int2 offp = {0, 0};
        __half2 h01 = __floats2half2_rn(0.f, 0.f);
        __half2 h23 = h01;
        if (qq < M) {
            const int Wi = (l == 0) ? 100 : (l == 1) ? 50 : (l == 2) ? 25
                         : (l == 3) ? 13 : 7;
            const int s0 = (l == 0) ? 0 : (l == 1) ? 10000 : (l == 2) ? 12500
                         : (l == 3) ? 13125 : 13294;
            const float Wf = (float)Wi;
            const float ox = us2f(og[(size_t)qq * 480 + r * 2]);
            const float oy = us2f(og[(size_t)qq * 480 + r * 2 + 1]);
            const float2 rf = *reinterpret_cast<const float2*>(
                &refp[(size_t)qq * 10 + l * 2]);
            const float a = s_attn[q][r];

            const float px = fmaf(rf.x, Wf, -0.5f) + ox;
            const float py = fmaf(rf.y, Wf, -0.5f) + oy;
            const float x0f = floorf(px);
            const float y0f = floorf(py);
            const float lx = px - x0f;
            const float ly = py - y0f;
            const int x0 = (int)x0f;
            const int y0 = (int)y0f;

            const float wx0v = (x0 >= 0 && x0 < Wi) ? (1.f - lx) : 0.f;
            const float wx1v = (x0 + 1 >= 0 && x0 + 1 < Wi) ? lx : 0.f;
            const float wy0v = (y0 >= 0 && y0 < Wi) ? (1.f - ly) : 0.f;
            const float wy1v = (y0 + 1 >= 0 && y0 + 1 < Wi) ? ly : 0.f;

            const int c0 = min(max(x0, 0), Wi - 2);
            const int r0 = min(max(y0, 0), Wi - 2);
            const float swx0 = (x0 == c0 ? wx0v : 0.f) + (x0 + 1 == c0 ? wx1v : 0.f);
            const float swx1 = (x0 == c0 + 1 ? wx0v : 0.f) + (x0 + 1 == c0 + 1 ? wx1v : 0.f);
            const float swy0 = (y0 == r0 ? wy0v : 0.f) + (y0 + 1 == r0 ? wy1v : 0.f);
            const float swy1 = (y0 == r0 + 1 ? wy0v : 0.f) + (y0 + 1 == r0 + 1 ? wy1v : 0.f);

            offp.x = (s0 + r0 * Wi + c0) * 512;
            offp.y = offp.x + Wi * 512;
            h01 = __floats2half2_rn(a * swx0 * swy0, a * swx1 * swy0);
            h23 = __floats2half2_rn(a * swx0 * swy1, a * swx1 * swy1);
        }
        s_off[t] = offp;
        union { __half2 h; int i; } c0u, c1u;
        c0u.h = h01; c1u.h = h23;
        int2 wpk; wpk.x = c0u.i; wpk.y = c1u.i;
        s_wh[t] = wpk;
    }
    __syncthreads();

    const int qi  = tid >> 5;
    const int g   = tid & 31;
    const int h   = g >> 2;
    const int sub = g & 3;
    const int bq = qbase + qi;
    if (bq >= M) return;
    const int b = bq / L;

    const char* vb = (const char*)value + (size_t)b * L * 512 + h * 64 + sub * 16;

    float acc[8] = {};
    const int tb = qi * 160 + h * 20;
    #pragma unroll 2
    for (int p = 0; p < 20; ++p) {
        const int2 off = s_off[tb + p];
        const int2 whp = s_wh[tb + p];
        const int4 u00 = *reinterpret_cast<const int4*>(vb + off.x);
        const int4 u10 = *reinterpret_cast<const int4*>(vb + off.x + 512);
        const int4 u01 = *reinterpret_cast<const int4*>(vb + off.y);
        const int4 u11 = *reinterpret_cast<const int4*>(vb + off.y + 512);
        union { int i; __half2 h; } w0u, w1u;
        w0u.i = whp.x; w1u.i = whp.y;
        const float2 w01 = __half22float2(w0u.h);
        const float2 w23 = __half22float2(w1u.h);
        #define ACC4(u, wt)                                                        \
            acc[0] = fmaf(wt, __uint_as_float((unsigned)(u).x << 16), acc[0]);      \
            acc[1] = fmaf(wt, __uint_as_float((unsigned)(u).x & 0xffff0000u), acc[1]); \
            acc[2] = fmaf(wt, __uint_as_float((unsigned)(u).y << 16), acc[2]);      \
            acc[3] = fmaf(wt, __uint_as_float((unsigned)(u).y & 0xffff0000u), acc[3]); \
            acc[4] = fmaf(wt, __uint_as_float((unsigned)(u).z << 16), acc[4]);      \
            acc[5] = fmaf(wt, __uint_as_float((unsigned)(u).z & 0xffff0000u), acc[5]); \
            acc[6] = fmaf(wt, __uint_as_float((unsigned)(u).w << 16), acc[6]);      \
            acc[7] = fmaf(wt, __uint_as_float((unsigned)(u).w & 0xffff0000u), acc[7]);
        ACC4(u00, w01.x)
        ACC4(u10, w01.y)
        ACC4(u01, w23.x)
        ACC4(u11, w23.y)
        #undef ACC4
    }

    ushort_t o[8];
    #pragma unroll
    for (int i = 0; i < 8; ++i) o[i] = f2us(acc[i]);
    int4 pkt;
    pkt.x = (int)o[0] | ((int)o[1] << 16);
    pkt.y = (int)o[2] | ((int)o[3] << 16);
    pkt.z = (int)o[4] | ((int)o[5] << 16);
    pkt.w = (int)o[6] | ((int)o[7] << 16);
    *reinterpret_cast<int4*>((ushort_t*)out + (size_t)bq * 256 + h * 32 + sub * 8) = pkt;
}

// ---------------------------------------------------------------------------
// LayerNorm over 256, bf16 input. Block = 4 waves = 4 rows, wave-per-row,
// shuffle-only. OUT_BF16: bf16 out (LN1->x_b) else f32 out (LN2->d_out).
// ---------------------------------------------------------------------------
template<bool OUT_BF16>
__global__ __launch_bounds__(256) void ln_kernel(
    const ushort_t* __restrict__ yb, const float* __restrict__ g,
    const float* __restrict__ bta, void* __restrict__ outv, int M)
{
    const int wave = threadIdx.x >> 6, lane = threadIdx.x & 63;
    const int row = blockIdx.x * 4 + wave;
    if (row >= M) return;
    const int2 raw = *reinterpret_cast<const int2*>(&yb[(size_t)row * 256 + lane * 4]);
    float v0 = us2f((ushort_t)((unsigned)raw.x & 0xffffu));
    float v1 = us2f((ushort_t)((unsigned)raw.x >> 16));
    float v2 = us2f((ushort_t)((unsigned)raw.y & 0xffffu));
    float v3 = us2f((ushort_t)((unsigned)raw.y >> 16));
    float s  = v0 + v1 + v2 + v3;
    float ss = v0 * v0 + v1 * v1 + v2 * v2 + v3 * v3;
    #pragma unroll
    for (int o = 32; o > 0; o >>= 1) {
        s += __shfl_down(s, o);
        ss += __shfl_down(ss, o);
    }
    s = __shfl(s, 0);
    ss = __shfl(ss, 0);
    const float mean = s * (1.f / 256.f);
    const float var = ss * (1.f / 256.f) - mean * mean;
    const float rs = rsqrtf(var + 1e-5f);
    const float4 g4 = *reinterpret_cast<const float4*>(&g[lane * 4]);
    const float4 b4 = *reinterpret_cast<const float4*>(&bta[lane * 4]);
    float4 o4;
    o4.x = (v0 - mean) * rs * g4.x + b4.x;
    o4.y = (v1 - mean) * rs * g4.y + b4.y;
    o4.z = (v2 - mean) * rs * g4.z + b4.z;
    o4.w = (v3 - mean) * rs * g4.w + b4.w;
    if (OUT_BF16) {
        int2 pk;
        pk.x = (unsigned)f2us(o4.x) | ((unsigned)f2us(o4.y) << 16);
        pk.y = (unsigned)f2us(o4.z) | ((unsigned)f2us(o4.w) << 16);
        *reinterpret_cast<int2*>((ushort_t*)outv + (size_t)row * 256 + lane * 4) = pk;
    } else {
        *reinterpret_cast<float4*>((float*)outv + (size_t)row * 256 + lane * 4) = o4;
    }
}

// ---------------------------------------------------------------------------
extern "C" void kernel_launch(void* const* d_in, const int* in_sizes, int n_in,
                              void* d_out, int out_size, void* d_ws, size_t ws_size,
                              hipStream_t stream)
{
    const int B = 2, L = 13343, C = 256, FF = 2048;
    const int M = B * L;  // 26686

    const float* src  = (const float*)d_in[0];
    const float* pos  = (const float*)d_in[1];
    const float* refp = (const float*)d_in[2];
    const float* wv   = (const float*)d_in[3];
    const float* bv   = (const float*)d_in[4];
    const float* wo   = (const float*)d_in[5];
    const float* bo   = (const float*)d_in[6];
    const float* wa   = (const float*)d_in[7];
    const float* ba   = (const float*)d_in[8];
    const float* wout = (const float*)d_in[9];
    const float* bout = (const float*)d_in[10];
    const float* ln1g = (const float*)d_in[11];
    const float* ln1b = (const float*)d_in[12];
    const float* w1   = (const float*)d_in[13];
    const float* b1   = (const float*)d_in[14];
    const float* w2   = (const float*)d_in[15];
    const float* b2   = (const float*)d_in[16];
    const float* ln2g = (const float*)d_in[17];
    const float* ln2b = (const float*)d_in[18];

    char* ws = (char*)d_ws;
    const size_t MB = 1ull << 20;
    // ---- workspace overlay (peak ~155 MB) ----
    bf16*  src_b  = (bf16*)(ws + 0);         // 13.7 MB
    bf16*  q_b    = (bf16*)(ws + 14 * MB);   // 13.7
    bf16*  val_b  = (bf16*)(ws + 28 * MB);   // 13.7
    bf16*  og     = (bf16*)(ws + 42 * MB);   // M*480 bf16 = 25.6 -> ends 67.6
    bf16*  acc_b  = (bf16*)(ws + 95 * MB);   // 13.7 -> ends 108.7
    bf16*  h_b    = (bf16*)(ws + 0);         // M*2048 bf16 = 109.3 (overlays dead)
    bf16*  y      = (bf16*)(ws + 110 * MB);  // 13.7 bf16 (dead after LN1)
    bf16*  z      = (bf16*)(ws + 110 * MB);  // overlays y (bf16)
    bf16*  x_b    = (bf16*)(ws + 138 * MB);  // 13.7 (resid + FFN1 input)
    bf16* wvt    = (bf16*)(ws + 152 * MB);   // 256*256
    bf16* wcat   = wvt + 256 * 256;          // 480*256
    bf16* woutt  = wcat + 480 * 256;         // 256*256
    bf16* w1t    = woutt + 256 * 256;        // 2048*256
    bf16* w2t    = w1t + 2048 * 256;         // 256*2048
    float* bcat  = (float*)(w2t + 256 * 2048); // 480 f32, ends ~154.6 MB
    (void)ws_size; (void)n_in; (void)in_sizes; (void)out_size;

    const int mt64 = (M + 63) / 64;        // 417
    const int gm8  = (mt64 + 7) / 8;       // 53
    const int lnb  = (M + 3) / 4;          // 6672

    // ---- fused weight prep (one launch) ----
    prep_kernel<<<1274, 256, 0, stream>>>(wv, wo, wa, wout, w1, w2, bo, ba,
                                          wvt, wcat, woutt, w1t, w2t, bcat);

    // ---- fused activation casts (float4) ----
    cast2_kernel<<<(M * C / 4 + 255) / 256, 256, 0, stream>>>(
        src, pos, src_b, q_b, M * C);

    // value = src @ wv + bv  (bf16)  [NT=2]
    gemm_mfma_s<false, true, false, false, 2, 4><<<gm8 * 16, 256, 0, stream>>>(
        (const ushort_t*)src_b, (const ushort_t*)wvt, bv, nullptr, val_b,
        M, 256, 256, mt64);

    // og = q @ [wo|wa] + [bo|ba]  (bf16, N=480)  [NT=4]
    gemm_mfma_s<false, true, false, false, 4, 4><<<gm8 * 32, 256, 0, stream>>>(
        (const ushort_t*)q_b, (const ushort_t*)wcat, bcat, nullptr, og,
        M, 480, 256, mt64);

    // deformable attention -> acc_b (bf16)  [batch->XCD remap]
    msda_kernel_v7<<<(M + 7) / 8, 256, 0, stream>>>(
        (const ushort_t*)og, refp, (const ushort_t*)val_b, acc_b, M, L);

    // y = acc @ wout + bout + src  (bf16 out, f32 resid)  [NT=2]
    gemm_mfma_s<false, true, true, false, 2, 4><<<gm8 * 16, 256, 0, stream>>>(
        (const ushort_t*)acc_b, (const ushort_t*)woutt, bout, src, y,
        M, 256, 256, mt64);

    // x_b = LN1(y)  (bf16 in, bf16 out)
    ln_kernel<true><<<lnb, 256, 0, stream>>>(
        (const ushort_t*)y, ln1g, ln1b, x_b, M);

    // h = relu(x @ w1 + b1)  (bf16, N=2048)  [NT=16]
    gemm_mfma_s<true, true, false, false, 16, 4><<<gm8 * 128, 256, 0, stream>>>(
        (const ushort_t*)x_b, (const ushort_t*)w1t, b1, nullptr, h_b,
        M, FF, 256, mt64);

    // z = h @ w2 + b2 + x  (bf16 out, bf16 resid = x_b)  [NT=2]
    gemm_mfma_s<false, true, true, true, 2, 4><<<gm8 * 16, 256, 0, stream>>>(
        (const ushort_t*)h_b, (const ushort_t*)w2t, b2, x_b, z,
        M, 256, FF, mt64);

    // out = LN2(z)  (bf16 in, f32 out)
    ln_kernel<false><<<lnb, 256, 0, stream>>>(
        (const ushort_t*)z, ln2g, ln2b, (float*)d_out, M);
}

// Round 7
// 353.642 us; speedup vs baseline: 1.0365x; 1.0009x over previous
//
#include <hip/hip_runtime.h>
#include <hip/hip_bf16.h>
#include <hip/hip_fp16.h>

typedef __hip_bfloat16 bf16;
typedef unsigned short ushort_t;
typedef __attribute__((ext_vector_type(8))) short bf16x8;
typedef __attribute__((ext_vector_type(16))) float f32x16;

__device__ __forceinline__ float us2f(unsigned short u) {
    unsigned int x = ((unsigned int)u) << 16;
    return __uint_as_float(x);
}
__device__ __forceinline__ ushort_t f2us(float f) {
    return ((__hip_bfloat16_raw)__float2bfloat16(f)).x;
}

// async global->LDS, 16 B per lane. LDS dest = wave-uniform base + lane*16.
__device__ __forceinline__ void gl_lds16(const ushort_t* g, ushort_t* l) {
    __builtin_amdgcn_global_load_lds(
        (const __attribute__((address_space(1))) void*)g,
        (__attribute__((address_space(3))) void*)l, 16, 0, 0);
}

// ---------------------------------------------------------------------------
// Fused input cast (float4): src_b = bf16(src), q_b = bf16(src + pos)
// ---------------------------------------------------------------------------
__global__ __launch_bounds__(256) void cast2_kernel(
    const float* __restrict__ src, const float* __restrict__ pos,
    bf16* __restrict__ src_b, bf16* __restrict__ q_b, int n)
{
    int i = (blockIdx.x * 256 + threadIdx.x) * 4;
    if (i < n) {
        const float4 s4 = *reinterpret_cast<const float4*>(&src[i]);
        const float4 p4 = *reinterpret_cast<const float4*>(&pos[i]);
        int2 sp, qp;
        sp.x = (unsigned)f2us(s4.x) | ((unsigned)f2us(s4.y) << 16);
        sp.y = (unsigned)f2us(s4.z) | ((unsigned)f2us(s4.w) << 16);
        qp.x = (unsigned)f2us(s4.x + p4.x) | ((unsigned)f2us(s4.y + p4.y) << 16);
        qp.y = (unsigned)f2us(s4.z + p4.z) | ((unsigned)f2us(s4.w + p4.w) << 16);
        *reinterpret_cast<int2*>((ushort_t*)src_b + i) = sp;
        *reinterpret_cast<int2*>((ushort_t*)q_b + i) = qp;
    }
}

// ---------------------------------------------------------------------------
// Fused weight prep: all transpose-casts + bias concat in ONE launch.
// ---------------------------------------------------------------------------
__global__ __launch_bounds__(256) void prep_kernel(
    const float* __restrict__ wv, const float* __restrict__ wo,
    const float* __restrict__ wa, const float* __restrict__ wout,
    const float* __restrict__ w1, const float* __restrict__ w2,
    const float* __restrict__ bo, const float* __restrict__ ba,
    bf16* __restrict__ wvt, bf16* __restrict__ wcat, bf16* __restrict__ woutt,
    bf16* __restrict__ w1t, bf16* __restrict__ w2t, float* __restrict__ bcat)
{
    __shared__ float tile[32][33];
    const int b = blockIdx.x;
    const float* W; bf16* Wt; int K, N, tb;
    if (b < 64)        { W = wv;   Wt = wvt;            K = 256;  N = 256;  tb = b; }
    else if (b < 144)  { W = wo;   Wt = wcat;           K = 256;  N = 320;  tb = b - 64; }
    else if (b < 184)  { W = wa;   Wt = wcat + 320*256; K = 256;  N = 160;  tb = b - 144; }
    else if (b < 248)  { W = wout; Wt = woutt;          K = 256;  N = 256;  tb = b - 184; }
    else if (b < 760)  { W = w1;   Wt = w1t;            K = 256;  N = 2048; tb = b - 248; }
    else if (b < 1272) { W = w2;   Wt = w2t;            K = 2048; N = 256;  tb = b - 760; }
    else {
        int i = (b - 1272) * 256 + threadIdx.x;
        if (i < 320) bcat[i] = bo[i];
        else if (i < 480) bcat[i] = ba[i - 320];
        return;
    }
    const int ntn = N >> 5;
    const int nb = (tb % ntn) * 32, kb = (tb / ntn) * 32;
    const int tx = threadIdx.x & 31, ty = threadIdx.x >> 5;  // 32 x 8
    #pragma unroll
    for (int i = 0; i < 32; i += 8) {
        int k = kb + ty + i, n = nb + tx;
        tile[ty + i][tx] = (k < K && n < N) ? W[(size_t)k * N + n] : 0.f;
    }
    __syncthreads();
    #pragma unroll
    for (int i = 0; i < 32; i += 8) {
        int n = nb + ty + i, k = kb + tx;
        if (n < N && k < K)
            Wt[(size_t)n * K + k] = __float2bfloat16(tile[tx][ty + i]);
    }
}

// ---------------------------------------------------------------------------
// MFMA bf16 GEMM (64x128 tile, M-split), swizzled-LDS, double-buffered.
// (proven R5/R6 kernel — used for the small N=256,K=256 GEMMs)
// ---------------------------------------------------------------------------
template<bool RELU, bool OUT_BF16, bool HAS_RESID, bool RESID_BF16, int NT, int WPE>
__global__ __launch_bounds__(256, WPE) void gemm_mfma_s(
    const ushort_t* __restrict__ A,    // [M][K] bf16
    const ushort_t* __restrict__ Bt,   // [N][K] bf16
    const float* __restrict__ bias,    // [N] f32
    const void* __restrict__ residv,   // [M][N] f32 or bf16
    void* __restrict__ outv, int M, int N, int K, int mtiles)
{
    __shared__ __align__(16) char smemraw[24576];
    ushort_t* Asmem = (ushort_t*)smemraw;          // buf0: A 4 KB @0, B 8 KB @4096
    ushort_t* Bsmem = (ushort_t*)(smemraw + 4096); // buf1 at +12288 B (+6144 us)
    float (*epi)[68] = (float(*)[68])smemraw;      // 64 x 68 f32 = 17408 B overlay

    const int lid = blockIdx.x;
    const int tbk = lid >> 3;
    const int xb = tbk & (NT - 1);
    const int yg = (tbk / NT) * 8 + (lid & 7);
    if (yg >= mtiles) return;
    const int m0 = yg * 64;
    const int n0 = xb * 128;

    const int tid = threadIdx.x;
    const int lane = tid & 63;
    const int wave = tid >> 6;
    const int l32 = lane & 31;
    const int hi  = lane >> 5;
    const int wm = wave >> 1;
    const int wn = wave & 1;

    const int lsup = lane >> 3;
    const int clin = lane & 7;

    const int gsA = wave * 8 + lsup;
    const int csA = clin ^ (gsA & 7);
    int rA = m0 + gsA * 2 + (csA >> 2); if (rA > M - 1) rA = M - 1;
    const ushort_t* aP = A + (size_t)rA * K + (csA & 3) * 8;
    ushort_t* aL = Asmem + wave * 512;

    const ushort_t* bP[2]; ushort_t* bL[2];
    #pragma unroll
    for (int i = 0; i < 2; ++i) {
        const int gsB = wave * 16 + i * 8 + lsup;
        const int csB = clin ^ (gsB & 7);
        int rB = n0 + gsB * 2 + (csB >> 2); if (rB > N - 1) rB = N - 1;
        bP[i] = Bt + (size_t)rB * K + (csB & 3) * 8;
        bL[i] = Bsmem + (wave * 16 + i * 8) * 64;
    }

    const int arow = wm * 32 + l32;
    const int asup = arow >> 1;
    const ushort_t* aR[2];
    #pragma unroll
    for (int kw = 0; kw < 2; ++kw) {
        const int q = kw * 2 + hi;
        const int slot = (((arow & 1) << 2) | q) ^ (asup & 7);
        aR[kw] = Asmem + asup * 64 + slot * 8;
    }
    const ushort_t* bR[2][2];
    #pragma unroll
    for (int j = 0; j < 2; ++j) {
        const int brow = wn * 64 + j * 32 + l32;
        const int bsup = brow >> 1;
        #pragma unroll
        for (int kw = 0; kw < 2; ++kw) {
            const int q = kw * 2 + hi;
            const int slot = (((brow & 1) << 2) | q) ^ (bsup & 7);
            bR[j][kw] = Bsmem + bsup * 64 + slot * 8;
        }
    }

    f32x16 acc[2] = {};

    auto stage = [&](int ofs) {
        gl_lds16(aP, aL + ofs);             aP    += 32;
        gl_lds16(bP[0], bL[0] + ofs);       bP[0] += 32;
        gl_lds16(bP[1], bL[1] + ofs);       bP[1] += 32;
    };
    auto compute = [&](int ofs) {
        #pragma unroll
        for (int kw = 0; kw < 2; ++kw) {
            const bf16x8 af = *reinterpret_cast<const bf16x8*>(aR[kw] + ofs);
            #pragma unroll
            for (int j = 0; j < 2; ++j)
                acc[j] = __builtin_amdgcn_mfma_f32_32x32x16_bf16(
                    af, *reinterpret_cast<const bf16x8*>(bR[j][kw] + ofs),
                    acc[j], 0, 0, 0);
        }
    };

    const int ntile = K >> 5;
    stage(0);
    for (int t = 0; t < ntile; t += 2) {
        __syncthreads();
        stage(6144);
        compute(0);
        __syncthreads();
        if (t + 2 < ntile) stage(0);
        compute(6144);
    }
    __syncthreads();

    #pragma unroll
    for (int half = 0; half < 2; ++half) {
        if (wn == half) {
            #pragma unroll
            for (int j = 0; j < 2; ++j) {
                const int coll = j * 32 + l32;
                const int n = n0 + half * 64 + coll;
                const float bv = (n < N) ? bias[n] : 0.f;
                #pragma unroll
                for (int r = 0; r < 16; ++r) {
                    const int row = wm * 32 + hi * 4 + (r & 3) + (r >> 2) * 8;
                    epi[row][coll] = acc[j][r] + bv;
                }
            }
        }
        __syncthreads();
        #pragma unroll
        for (int i = 0; i < 4; ++i) {
            const int idx = i * 256 + tid;
            const int row = idx >> 4;
            const int c4  = idx & 15;
            const int m = m0 + row;
            const int n = n0 + half * 64 + c4 * 4;
            if (m < M && n + 3 < N) {
                float4 v = *reinterpret_cast<const float4*>(&epi[row][c4 * 4]);
                if (HAS_RESID) {
                    if (RESID_BF16) {
                        const int2 rw = *reinterpret_cast<const int2*>(
                            (const ushort_t*)residv + (size_t)m * N + n);
                        v.x += us2f((ushort_t)((unsigned)rw.x & 0xffffu));
                        v.y += us2f((ushort_t)((unsigned)rw.x >> 16));
                        v.z += us2f((ushort_t)((unsigned)rw.y & 0xffffu));
                        v.w += us2f((ushort_t)((unsigned)rw.y >> 16));
                    } else {
                        const float4 r4 = *reinterpret_cast<const float4*>(
                            (const float*)residv + (size_t)m * N + n);
                        v.x += r4.x; v.y += r4.y; v.z += r4.z; v.w += r4.w;
                    }
                }
                if (RELU) {
                    v.x = fmaxf(v.x, 0.f); v.y = fmaxf(v.y, 0.f);
                    v.z = fmaxf(v.z, 0.f); v.w = fmaxf(v.w, 0.f);
                }
                if (OUT_BF16) {
                    int2 pk;
                    pk.x = (unsigned)f2us(v.x) | ((unsigned)f2us(v.y) << 16);
                    pk.y = (unsigned)f2us(v.z) | ((unsigned)f2us(v.w) << 16);
                    *reinterpret_cast<int2*>((ushort_t*)outv + (size_t)m * N + n) = pk;
                } else {
                    *reinterpret_cast<float4*>((float*)outv + (size_t)m * N + n) = v;
                }
            }
        }
        if (half == 0) __syncthreads();
    }
}

// ---------------------------------------------------------------------------
// BIG MFMA bf16 GEMM: 128x128 tile, 4 waves, 64x64 per wave (2x2 of 32x32).
// Same swizzle (super-row mod-8, scale-invariant), same dbuf 2-barrier loop,
// same staging pattern (2 gl_lds16 per operand per thread). Per K-step per
// block: 32 ds_read_b128 vs 32 MFMA (was 24:16) -> 1.5x less LDS pressure
// per FLOP + 2x global reuse. Epilogue: 4 quadrant passes of the proven
// [64][68] f32 repack (each wave owns exactly one 64x64 quadrant).
// LDS 32 KB, ~110 VGPR -> 4 blocks/CU.
// ---------------------------------------------------------------------------
template<bool RELU, bool OUT_BF16, bool HAS_RESID, bool RESID_BF16, int NT>
__global__ __launch_bounds__(256, 4) void gemm_mfma_b(
    const ushort_t* __restrict__ A,    // [M][K] bf16
    const ushort_t* __restrict__ Bt,   // [N][K] bf16
    const float* __restrict__ bias,    // [N] f32
    const void* __restrict__ residv,   // [M][N] f32 or bf16
    void* __restrict__ outv, int M, int N, int K, int mtiles)
{
    __shared__ __align__(16) char smemraw[32768];
    ushort_t* Asmem = (ushort_t*)smemraw;            // buf0: A 8 KB @0
    ushort_t* Bsmem = (ushort_t*)(smemraw + 8192);   // buf0: B 8 KB @8192
    float (*epi)[68] = (float(*)[68])smemraw;        // 64 x 68 f32 overlay
    // buf1 = buf0 + 16384 B (= 8192 ushorts)

    const int lid = blockIdx.x;
    const int tbk = lid >> 3;
    const int xb = tbk & (NT - 1);
    const int yg = (tbk / NT) * 8 + (lid & 7);
    if (yg >= mtiles) return;
    const int m0 = yg * 128;
    const int n0 = xb * 128;

    const int tid = threadIdx.x;
    const int lane = tid & 63;
    const int wave = tid >> 6;
    const int l32 = lane & 31;
    const int hi  = lane >> 5;
    const int wm = wave >> 1;
    const int wn = wave & 1;

    // ---- staging (pre-swizzled global src, linear LDS dest) ----
    const int lsup = lane >> 3;
    const int clin = lane & 7;
    const ushort_t *aP[2], *bP[2];
    ushort_t *aL[2], *bL[2];
    #pragma unroll
    for (int i = 0; i < 2; ++i) {
        const int gs = wave * 16 + i * 8 + lsup;      // super-row 0..63
        const int cs = clin ^ (gs & 7);               // source slot
        int rA = m0 + gs * 2 + (cs >> 2); if (rA > M - 1) rA = M - 1;
        aP[i] = A + (size_t)rA * K + (cs & 3) * 8;
        aL[i] = Asmem + (wave * 16 + i * 8) * 64;
        int rB = n0 + gs * 2 + (cs >> 2); if (rB > N - 1) rB = N - 1;
        bP[i] = Bt + (size_t)rB * K + (cs & 3) * 8;
        bL[i] = Bsmem + (wave * 16 + i * 8) * 64;
    }

    // ---- fragment read addresses (swizzled, loop-invariant) ----
    const ushort_t* aR[2][2];
    const ushort_t* bR[2][2];
    #pragma unroll
    for (int mi = 0; mi < 2; ++mi) {
        const int arow = wm * 64 + mi * 32 + l32;
        const int asup = arow >> 1;
        #pragma unroll
        for (int kw = 0; kw < 2; ++kw) {
            const int q = kw * 2 + hi;
            const int slot = (((arow & 1) << 2) | q) ^ (asup & 7);
            aR[mi][kw] = Asmem + asup * 64 + slot * 8;
        }
    }
    #pragma unroll
    for (int ni = 0; ni < 2; ++ni) {
        const int brow = wn * 64 + ni * 32 + l32;
        const int bsup = brow >> 1;
        #pragma unroll
        for (int kw = 0; kw < 2; ++kw) {
            const int q = kw * 2 + hi;
            const int slot = (((brow & 1) << 2) | q) ^ (bsup & 7);
            bR[ni][kw] = Bsmem + bsup * 64 + slot * 8;
        }
    }

    f32x16 a00 = {}, a01 = {}, a10 = {}, a11 = {};

    auto stage = [&](int ofs) {  // ofs in ushorts: 0 = buf0, 8192 = buf1
        gl_lds16(aP[0], aL[0] + ofs); aP[0] += 32;
        gl_lds16(aP[1], aL[1] + ofs); aP[1] += 32;
        gl_lds16(bP[0], bL[0] + ofs); bP[0] += 32;
        gl_lds16(bP[1], bL[1] + ofs); bP[1] += 32;
    };
    auto compute = [&](int ofs) {
        #pragma unroll
        for (int kw = 0; kw < 2; ++kw) {
            const bf16x8 af0 = *reinterpret_cast<const bf16x8*>(aR[0][kw] + ofs);
            const bf16x8 af1 = *reinterpret_cast<const bf16x8*>(aR[1][kw] + ofs);
            const bf16x8 bf0 = *reinterpret_cast<const bf16x8*>(bR[0][kw] + ofs);
            const bf16x8 bf1 = *reinterpret_cast<const bf16x8*>(bR[1][kw] + ofs);
            a00 = __builtin_amdgcn_mfma_f32_32x32x16_bf16(af0, bf0, a00, 0, 0, 0);
            a01 = __builtin_amdgcn_mfma_f32_32x32x16_bf16(af0, bf1, a01, 0, 0, 0);
            a10 = __builtin_amdgcn_mfma_f32_32x32x16_bf16(af1, bf0, a10, 0, 0, 0);
            a11 = __builtin_amdgcn_mfma_f32_32x32x16_bf16(af1, bf1, a11, 0, 0, 0);
        }
    };

    const int ntile = K >> 5;          // even (K = 256 or 2048)
    stage(0);
    for (int t = 0; t < ntile; t += 2) {
        __syncthreads();
        stage(8192);
        compute(0);
        __syncthreads();
        if (t + 2 < ntile) stage(0);
        compute(8192);
    }
    __syncthreads();

    // ---- epilogue: 4 quadrant passes through [64][68] f32 repack ----
    #pragma unroll
    for (int qd = 0; qd < 4; ++qd) {
        const int rh = qd >> 1, ch = qd & 1;
        if (qd) __syncthreads();
        if (wm == rh && wn == ch) {
            #pragma unroll
            for (int ni = 0; ni < 2; ++ni) {
                const int col = ni * 32 + l32;
                const int n = n0 + ch * 64 + col;
                const float bv = (n < N) ? bias[n] : 0.f;
                #pragma unroll
                for (int mi = 0; mi < 2; ++mi) {
                    const f32x16& ac = (mi == 0) ? (ni == 0 ? a00 : a01)
                                                 : (ni == 0 ? a10 : a11);
                    #pragma unroll
                    for (int r = 0; r < 16; ++r) {
                        const int row = mi * 32 + hi * 4 + (r & 3) + (r >> 2) * 8;
                        epi[row][col] = ac[r] + bv;
                    }
                }
            }
        }
        __syncthreads();
        #pragma unroll
        for (int i = 0; i < 4; ++i) {
            const int idx = i * 256 + tid;
            const int row = idx >> 4;
            const int c4  = idx & 15;
            const int m = m0 + rh * 64 + row;
            const int n = n0 + ch * 64 + c4 * 4;
            if (m < M && n + 3 < N) {
                float4 v = *reinterpret_cast<const float4*>(&epi[row][c4 * 4]);
                if (HAS_RESID) {
                    if (RESID_BF16) {
                        const int2 rw = *reinterpret_cast<const int2*>(
                            (const ushort_t*)residv + (size_t)m * N + n);
                        v.x += us2f((ushort_t)((unsigned)rw.x & 0xffffu));
                        v.y += us2f((ushort_t)((unsigned)rw.x >> 16));
                        v.z += us2f((ushort_t)((unsigned)rw.y & 0xffffu));
                        v.w += us2f((ushort_t)((unsigned)rw.y >> 16));
                    } else {
                        const float4 r4 = *reinterpret_cast<const float4*>(
                            (const float*)residv + (size_t)m * N + n);
                        v.x += r4.x; v.y += r4.y; v.z += r4.z; v.w += r4.w;
                    }
                }
                if (RELU) {
                    v.x = fmaxf(v.x, 0.f); v.y = fmaxf(v.y, 0.f);
                    v.z = fmaxf(v.z, 0.f); v.w = fmaxf(v.w, 0.f);
                }
                if (OUT_BF16) {
                    int2 pk;
                    pk.x = (unsigned)f2us(v.x) | ((unsigned)f2us(v.y) << 16);
                    pk.y = (unsigned)f2us(v.z) | ((unsigned)f2us(v.w) << 16);
                    *reinterpret_cast<int2*>((ushort_t*)outv + (size_t)m * N + n) = pk;
                } else {
                    *reinterpret_cast<float4*>((float*)outv + (size_t)m * N + n) = v;
                }
            }
        }
    }
}

// ---------------------------------------------------------------------------
// MS-deformable attention v7 (unchanged — at structural gather limit).
// ---------------------------------------------------------------------------
__global__ __launch_bounds__(256) void msda_kernel_v7(
    const ushort_t* __restrict__ og,     // [M,480] bf16: offs 0..319, logits 320..479
    const float* __restrict__ refp,      // [M,10]
    const ushort_t* __restrict__ value,  // [M,256] bf16 = (B,L,H,32)
    bf16* __restrict__ out,              // [M,256] bf16
    int M, int L)
{
    const int tid = threadIdx.x;
    const int nb = gridDim.x;
    int wk = blockIdx.x;
    if ((nb & 7) == 0) {                       // bijective XCD remap
        const int per = nb >> 3;
        wk = (blockIdx.x & 7) * per + (blockIdx.x >> 3);
    }
    const int qbase = wk * 8;

    __shared__ float s_attn[8][160];   // 5120 B
    __shared__ int2  s_off[1280];      // 10240 B
    __shared__ int2  s_wh[1280];       // 10240 B -> total 25600 B

    for (int i = tid; i < 1280; i += 256) {
        int q = i / 160, j = i - q * 160;
        int qq = qbase + q;
        s_attn[q][j] = (qq < M) ? us2f(og[(size_t)qq * 480 + 320 + j]) : 0.f;
    }
    __syncthreads();

    if (tid < 64) {
        float* a = &s_attn[tid >> 3][(tid & 7) * 20];
        float mx = -1e30f;
        #pragma unroll
        for (int i = 0; i < 20; ++i) mx = fmaxf(mx, a[i]);
        float ssum = 0.f;
        #pragma unroll
        for (int i = 0; i < 20; ++i) {
            float e = __expf(a[i] - mx);
            a[i] = e;
            ssum += e;
        }
        float inv = 1.f / ssum;
        #pragma unroll
        for (int i = 0; i < 20; ++i) a[i] *= inv;
    }
    __syncthreads();

    #pragma unroll
    for (int it = 0; it < 5; ++it) {
        const int t = tid + it * 256;
        const int q  = t / 160;
        const int r  = t - q * 160;
        const int l  = (r - (r / 20) * 20) >> 2;
        const int qq = qbase + q;

        int2 offp = {0, 0};
        __half2 h01 = __floats2half2_rn(0.f, 0.f);
        __half2 h23 = h01;
        if (qq < M) {
            const int Wi = (l == 0) ? 100 : (l == 1) ? 50 : (l == 2) ? 25
                         : (l == 3) ? 13 : 7;
            const int s0 = (l == 0) ? 0 : (l == 1) ? 10000 : (l == 2) ? 12500
                         : (l == 3) ? 13125 : 13294;
            const float Wf = (float)Wi;
            const float ox = us2f(og[(size_t)qq * 480 + r * 2]);
            const float oy = us2f(og[(size_t)qq * 480 + r * 2 + 1]);
            const float2 rf = *reinterpret_cast<const float2*>(
                &refp[(size_t)qq * 10 + l * 2]);
            const float a = s_attn[q][r];

            const float px = fmaf(rf.x, Wf, -0.5f) + ox;
            const float py = fmaf(rf.y, Wf, -0.5f) + oy;
            const float x0f = floorf(px);
            const float y0f = floorf(py);
            const float lx = px - x0f;
            const float ly = py - y0f;
            const int x0 = (int)x0f;
            const int y0 = (int)y0f;

            const float wx0v = (x0 >= 0 && x0 < Wi) ? (1.f - lx) : 0.f;
            const float wx1v = (x0 + 1 >= 0 && x0 + 1 < Wi) ? lx : 0.f;
            const float wy0v = (y0 >= 0 && y0 < Wi) ? (1.f - ly) : 0.f;
            const float wy1v = (y0 + 1 >= 0 && y0 + 1 < Wi) ? ly : 0.f;

            const int c0 = min(max(x0, 0), Wi - 2);
            const int r0 = min(max(y0, 0), Wi - 2);
            const float swx0 = (x0 == c0 ? wx0v : 0.f) + (x0 + 1 == c0 ? wx1v : 0.f);
            const float swx1 = (x0 == c0 + 1 ? wx0v : 0.f) + (x0 + 1 == c0 + 1 ? wx1v : 0.f);
            const float swy0 = (y0 == r0 ? wy0v : 0.f) + (y0 + 1 == r0 ? wy1v : 0.f);
            const float swy1 = (y0 == r0 + 1 ? wy0v : 0.f) + (y0 + 1 == r0 + 1 ? wy1v : 0.f);

            offp.x = (s0 + r0 * Wi + c0) * 512;
            offp.y = offp.x + Wi * 512;
            h01 = __floats2half2_rn(a * swx0 * swy0, a * swx1 * swy0);
            h23 = __floats2half2_rn(a * swx0 * swy1, a * swx1 * swy1);
        }
        s_off[t] = offp;
        union { __half2 h; int i; } c0u, c1u;
        c0u.h = h01; c1u.h = h23;
        int2 wpk; wpk.x = c0u.i; wpk.y = c1u.i;
        s_wh[t] = wpk;
    }
    __syncthreads();

    const int qi  = tid >> 5;
    const int g   = tid & 31;
    const int h   = g >> 2;
    const int sub = g & 3;
    const int bq = qbase + qi;
    if (bq >= M) return;
    const int b = bq / L;

    const char* vb = (const char*)value + (size_t)b * L * 512 + h * 64 + sub * 16;

    float acc[8] = {};
    const int tb = qi * 160 + h * 20;
    #pragma unroll 2
    for (int p = 0; p < 20; ++p) {
        const int2 off = s_off[tb + p];
        const int2 whp = s_wh[tb + p];
        const int4 u00 = *reinterpret_cast<const int4*>(vb + off.x);
        const int4 u10 = *reinterpret_cast<const int4*>(vb + off.x + 512);
        const int4 u01 = *reinterpret_cast<const int4*>(vb + off.y);
        const int4 u11 = *reinterpret_cast<const int4*>(vb + off.y + 512);
        union { int i; __half2 h; } w0u, w1u;
        w0u.i = whp.x; w1u.i = whp.y;
        const float2 w01 = __half22float2(w0u.h);
        const float2 w23 = __half22float2(w1u.h);
        #define ACC4(u, wt)                                                        \
            acc[0] = fmaf(wt, __uint_as_float((unsigned)(u).x << 16), acc[0]);      \
            acc[1] = fmaf(wt, __uint_as_float((unsigned)(u).x & 0xffff0000u), acc[1]); \
            acc[2] = fmaf(wt, __uint_as_float((unsigned)(u).y << 16), acc[2]);      \
            acc[3] = fmaf(wt, __uint_as_float((unsigned)(u).y & 0xffff0000u), acc[3]); \
            acc[4] = fmaf(wt, __uint_as_float((unsigned)(u).z << 16), acc[4]);      \
            acc[5] = fmaf(wt, __uint_as_float((unsigned)(u).z & 0xffff0000u), acc[5]); \
            acc[6] = fmaf(wt, __uint_as_float((unsigned)(u).w << 16), acc[6]);      \
            acc[7] = fmaf(wt, __uint_as_float((unsigned)(u).w & 0xffff0000u), acc[7]);
        ACC4(u00, w01.x)
        ACC4(u10, w01.y)
        ACC4(u01, w23.x)
        ACC4(u11, w23.y)
        #undef ACC4
    }

    ushort_t o[8];
    #pragma unroll
    for (int i = 0; i < 8; ++i) o[i] = f2us(acc[i]);
    int4 pkt;
    pkt.x = (int)o[0] | ((int)o[1] << 16);
    pkt.y = (int)o[2] | ((int)o[3] << 16);
    pkt.z = (int)o[4] | ((int)o[5] << 16);
    pkt.w = (int)o[6] | ((int)o[7] << 16);
    *reinterpret_cast<int4*>((ushort_t*)out + (size_t)bq * 256 + h * 32 + sub * 8) = pkt;
}

// ---------------------------------------------------------------------------
// LayerNorm over 256, bf16 input. Block = 4 waves = 4 rows, wave-per-row,
// shuffle-only. OUT_BF16: bf16 out (LN1->x_b) else f32 out (LN2->d_out).
// ---------------------------------------------------------------------------
template<bool OUT_BF16>
__global__ __launch_bounds__(256) void ln_kernel(
    const ushort_t* __restrict__ yb, const float* __restrict__ g,
    const float* __restrict__ bta, void* __restrict__ outv, int M)
{
    const int wave = threadIdx.x >> 6, lane = threadIdx.x & 63;
    const int row = blockIdx.x * 4 + wave;
    if (row >= M) return;
    const int2 raw = *reinterpret_cast<const int2*>(&yb[(size_t)row * 256 + lane * 4]);
    float v0 = us2f((ushort_t)((unsigned)raw.x & 0xffffu));
    float v1 = us2f((ushort_t)((unsigned)raw.x >> 16));
    float v2 = us2f((ushort_t)((unsigned)raw.y & 0xffffu));
    float v3 = us2f((ushort_t)((unsigned)raw.y >> 16));
    float s  = v0 + v1 + v2 + v3;
    float ss = v0 * v0 + v1 * v1 + v2 * v2 + v3 * v3;
    #pragma unroll
    for (int o = 32; o > 0; o >>= 1) {
        s += __shfl_down(s, o);
        ss += __shfl_down(ss, o);
    }
    s = __shfl(s, 0);
    ss = __shfl(ss, 0);
    const float mean = s * (1.f / 256.f);
    const float var = ss * (1.f / 256.f) - mean * mean;
    const float rs = rsqrtf(var + 1e-5f);
    const float4 g4 = *reinterpret_cast<const float4*>(&g[lane * 4]);
    const float4 b4 = *reinterpret_cast<const float4*>(&bta[lane * 4]);
    float4 o4;
    o4.x = (v0 - mean) * rs * g4.x + b4.x;
    o4.y = (v1 - mean) * rs * g4.y + b4.y;
    o4.z = (v2 - mean) * rs * g4.z + b4.z;
    o4.w = (v3 - mean) * rs * g4.w + b4.w;
    if (OUT_BF16) {
        int2 pk;
        pk.x = (unsigned)f2us(o4.x) | ((unsigned)f2us(o4.y) << 16);
        pk.y = (unsigned)f2us(o4.z) | ((unsigned)f2us(o4.w) << 16);
        *reinterpret_cast<int2*>((ushort_t*)outv + (size_t)row * 256 + lane * 4) = pk;
    } else {
        *reinterpret_cast<float4*>((float*)outv + (size_t)row * 256 + lane * 4) = o4;
    }
}

// ---------------------------------------------------------------------------
extern "C" void kernel_launch(void* const* d_in, const int* in_sizes, int n_in,
                              void* d_out, int out_size, void* d_ws, size_t ws_size,
                              hipStream_t stream)
{
    const int B = 2, L = 13343, C = 256, FF = 2048;
    const int M = B * L;  // 26686

    const float* src  = (const float*)d_in[0];
    const float* pos  = (const float*)d_in[1];
    const float* refp = (const float*)d_in[2];
    const float* wv   = (const float*)d_in[3];
    const float* bv   = (const float*)d_in[4];
    const float* wo   = (const float*)d_in[5];
    const float* bo   = (const float*)d_in[6];
    const float* wa   = (const float*)d_in[7];
    const float* ba   = (const float*)d_in[8];
    const float* wout = (const float*)d_in[9];
    const float* bout = (const float*)d_in[10];
    const float* ln1g = (const float*)d_in[11];
    const float* ln1b = (const float*)d_in[12];
    const float* w1   = (const float*)d_in[13];
    const float* b1   = (const float*)d_in[14];
    const float* w2   = (const float*)d_in[15];
    const float* b2   = (const float*)d_in[16];
    const float* ln2g = (const float*)d_in[17];
    const float* ln2b = (const float*)d_in[18];

    char* ws = (char*)d_ws;
    const size_t MB = 1ull << 20;
    // ---- workspace overlay (peak ~155 MB) ----
    bf16*  src_b  = (bf16*)(ws + 0);         // 13.7 MB
    bf16*  q_b    = (bf16*)(ws + 14 * MB);   // 13.7
    bf16*  val_b  = (bf16*)(ws + 28 * MB);   // 13.7
    bf16*  og     = (bf16*)(ws + 42 * MB);   // M*480 bf16 = 25.6 -> ends 67.6
    bf16*  acc_b  = (bf16*)(ws + 95 * MB);   // 13.7 -> ends 108.7
    bf16*  h_b    = (bf16*)(ws + 0);         // M*2048 bf16 = 109.3 (overlays dead)
    bf16*  y      = (bf16*)(ws + 110 * MB);  // 13.7 bf16 (dead after LN1)
    bf16*  z      = (bf16*)(ws + 110 * MB);  // overlays y (bf16)
    bf16*  x_b    = (bf16*)(ws + 138 * MB);  // 13.7 (resid + FFN1 input)
    bf16* wvt    = (bf16*)(ws + 152 * MB);   // 256*256
    bf16* wcat   = wvt + 256 * 256;          // 480*256
    bf16* woutt  = wcat + 480 * 256;         // 256*256
    bf16* w1t    = woutt + 256 * 256;        // 2048*256
    bf16* w2t    = w1t + 2048 * 256;         // 256*2048
    float* bcat  = (float*)(w2t + 256 * 2048); // 480 f32, ends ~154.6 MB
    (void)ws_size; (void)n_in; (void)in_sizes; (void)out_size;

    const int mt64  = (M + 63) / 64;        // 417
    const int gm8   = (mt64 + 7) / 8;       // 53
    const int mt128 = (M + 127) / 128;      // 209
    const int gb8   = (mt128 + 7) / 8;      // 27
    const int lnb   = (M + 3) / 4;          // 6672

    // ---- fused weight prep (one launch) ----
    prep_kernel<<<1274, 256, 0, stream>>>(wv, wo, wa, wout, w1, w2, bo, ba,
                                          wvt, wcat, woutt, w1t, w2t, bcat);

    // ---- fused activation casts (float4) ----
    cast2_kernel<<<(M * C / 4 + 255) / 256, 256, 0, stream>>>(
        src, pos, src_b, q_b, M * C);

    // value = src @ wv + bv  (bf16)  [small kernel, NT=2]
    gemm_mfma_s<false, true, false, false, 2, 4><<<gm8 * 16, 256, 0, stream>>>(
        (const ushort_t*)src_b, (const ushort_t*)wvt, bv, nullptr, val_b,
        M, 256, 256, mt64);

    // og = q @ [wo|wa] + [bo|ba]  (bf16, N=480)  [BIG kernel, NT=4]
    gemm_mfma_b<false, true, false, false, 4><<<gb8 * 32, 256, 0, stream>>>(
        (const ushort_t*)q_b, (const ushort_t*)wcat, bcat, nullptr, og,
        M, 480, 256, mt128);

    // deformable attention -> acc_b (bf16)  [batch->XCD remap]
    msda_kernel_v7<<<(M + 7) / 8, 256, 0, stream>>>(
        (const ushort_t*)og, refp, (const ushort_t*)val_b, acc_b, M, L);

    // y = acc @ wout + bout + src  (bf16 out, f32 resid)  [small kernel, NT=2]
    gemm_mfma_s<false, true, true, false, 2, 4><<<gm8 * 16, 256, 0, stream>>>(
        (const ushort_t*)acc_b, (const ushort_t*)woutt, bout, src, y,
        M, 256, 256, mt64);

    // x_b = LN1(y)  (bf16 in, bf16 out)
    ln_kernel<true><<<lnb, 256, 0, stream>>>(
        (const ushort_t*)y, ln1g, ln1b, x_b, M);

    // h = relu(x @ w1 + b1)  (bf16, N=2048)  [BIG kernel, NT=16]
    gemm_mfma_b<true, true, false, false, 16><<<gb8 * 128, 256, 0, stream>>>(
        (const ushort_t*)x_b, (const ushort_t*)w1t, b1, nullptr, h_b,
        M, FF, 256, mt128);

    // z = h @ w2 + b2 + x  (bf16 out, bf16 resid = x_b)  [BIG kernel, NT=2]
    gemm_mfma_b<false, true, true, true, 2><<<gb8 * 16, 256, 0, stream>>>(
        (const ushort_t*)h_b, (const ushort_t*)w2t, b2, x_b, z,
        M, 256, FF, mt128);

    // out = LN2(z)  (bf16 in, f32 out)
    ln_kernel<false><<<lnb, 256, 0, stream>>>(
        (const ushort_t*)z, ln2g, ln2b, (float*)d_out, M);
}